// Round 4
// baseline (103.282 us; speedup 1.0000x reference)
//
#include <hip/hip_runtime.h>
#include <hip/hip_fp16.h>

// NCC loss, window 9, zero-padded separable box sums.
// Shapes: (2,1,160,160,160) f32. Output: scalar f32.
//
// K1: per d-slice fused W+H 2D 9x9 box sum of 5 product channels.
//     wsum (W-stage) AND intermediate A stored fp16 (sums <= 81; double
//     rounding ~1e-3 rel -> final loss err ~1e-5, threshold 1.9e-2).
//     LDS 28.8 KB -> 5 blocks/CU (was 42 KB -> 3).
// K2: D-axis sliding-window sum (8B half2x2 loads) fused with cc + reduce.
// ws layout: A[2][5][VOL] as half (82 MB) | partials[400] f32

#define DIM 160
#define HW  (160 * 160)
#define VOL (160 * 160 * 160)
#define VOLH2 (VOL / 2)
#define HWH2 (HW / 2)
#define NBATCH 2
#define TIL 32
#define STG 40
#define SEG 20
#define SEGS (DIM / SEG)

struct __align__(8) h2q { __half2 a, b; };

__device__ inline float4 ld4h(const __half* p) {
    h2q v = *(const h2q*)p;
    float2 lo = __half22float2(v.a), hi = __half22float2(v.b);
    return make_float4(lo.x, lo.y, hi.x, hi.y);
}

__global__ __launch_bounds__(256) void k1_boxsum2d(const float* __restrict__ I,
                                                   const float* __restrict__ J,
                                                   __half2* __restrict__ A) {
    __shared__ float sI[STG][STG];             // 6.4 KB
    __shared__ float sJ[STG][STG];             // 6.4 KB
    __shared__ __half wsumh[5][STG][STG];      // 16 KB

    const int tid = threadIdx.x;
    const int tx = blockIdx.x % 5, ty = blockIdx.x / 5;
    const int d = blockIdx.y;
    const int batch = blockIdx.z;
    const int h0 = ty * TIL, w0 = tx * TIL;
    const float* Ib = I + (size_t)batch * VOL + (size_t)d * HW;
    const float* Jb = J + (size_t)batch * VOL + (size_t)d * HW;

    // ---- stage 40x40 (zero halo), float4 loads ----
    for (int t = tid; t < 800; t += 256) {
        int which = t >= 400;
        int rem = which ? t - 400 : t;
        int r = rem / 10, q = rem - r * 10;
        int gh = h0 - 4 + r;
        int gw = w0 - 4 + 4 * q;
        float4 v = make_float4(0.f, 0.f, 0.f, 0.f);
        if (gh >= 0 && gh < DIM) {
            const float* p = (which ? Jb : Ib) + gh * DIM;
            if (gw >= 0 && gw + 3 < DIM) {
                v = *(const float4*)(p + gw);
            } else {
                if (gw + 0 >= 0 && gw + 0 < DIM) v.x = p[gw + 0];
                if (gw + 1 >= 0 && gw + 1 < DIM) v.y = p[gw + 1];
                if (gw + 2 >= 0 && gw + 2 < DIM) v.z = p[gw + 2];
                if (gw + 3 >= 0 && gw + 3 < DIM) v.w = p[gw + 3];
            }
        }
        float* dst = (which ? &sJ[0][0] : &sI[0][0]) + r * STG + 4 * q;
        *(float4*)dst = v;
    }
    __syncthreads();

    // ---- W-stage: 9-tap sliding sum along w, 40 rows x 32 interior cols ----
    for (int t = tid; t < 320; t += 256) {
        int r = t >> 3, g = t & 7;
        const float* rI = &sI[r][0];
        const float* rJ = &sJ[r][0];
        float a[12], b[12];
        *(float4*)&a[0] = *(const float4*)(rI + 4 * g);
        *(float4*)&a[4] = *(const float4*)(rI + 4 * g + 4);
        *(float4*)&a[8] = *(const float4*)(rI + 4 * g + 8);
        *(float4*)&b[0] = *(const float4*)(rJ + 4 * g);
        *(float4*)&b[4] = *(const float4*)(rJ + 4 * g + 4);
        *(float4*)&b[8] = *(const float4*)(rJ + 4 * g + 8);

        float o0[4], o1[4], o2[4], o3[4], o4[4];
        float s0 = 0.f, s1 = 0.f, s2 = 0.f, s3 = 0.f, s4 = 0.f;
#pragma unroll
        for (int k = 0; k < 9; ++k) {
            float x = a[k], y = b[k];
            s0 += x; s1 += y; s2 += x * x; s3 += y * y; s4 += x * y;
        }
        o0[0] = s0; o1[0] = s1; o2[0] = s2; o3[0] = s3; o4[0] = s4;
#pragma unroll
        for (int j = 1; j < 4; ++j) {
            float xl = a[j + 8], yl = b[j + 8], xt = a[j - 1], yt = b[j - 1];
            s0 += xl - xt;
            s1 += yl - yt;
            s2 += xl * xl - xt * xt;
            s3 += yl * yl - yt * yt;
            s4 += xl * yl - xt * yt;
            o0[j] = s0; o1[j] = s1; o2[j] = s2; o3[j] = s3; o4[j] = s4;
        }
        __half* wp = &wsumh[0][0][0] + r * STG + 4 * g;
#define STORE_CH(ch, o)                                                     \
        {                                                                   \
            h2q q_;                                                         \
            q_.a = __floats2half2_rn(o[0], o[1]);                           \
            q_.b = __floats2half2_rn(o[2], o[3]);                           \
            *(h2q*)(wp + ch * (STG * STG)) = q_;                            \
        }
        STORE_CH(0, o0) STORE_CH(1, o1) STORE_CH(2, o2)
        STORE_CH(3, o3) STORE_CH(4, o4)
#undef STORE_CH
    }
    __syncthreads();

    // ---- H-stage: 2h x 2w per thread, 9-tap + 1 slide, store half2 ----
    {
        const int wq = tid & 15;       // w-pair
        const int hq = tid >> 4;       // h-pair (0..15)
        const int hsub = 2 * hq;
        const size_t obase = (size_t)batch * 5 * VOLH2 + (size_t)d * HWH2 +
                             (size_t)(h0 + hsub) * (DIM / 2) + (size_t)(tx * 16 + wq);
#pragma unroll
        for (int ch = 0; ch < 5; ++ch) {
            const __half* wp = &wsumh[ch][0][0] + 2 * wq;
            float rx[10], ry[10];
#pragma unroll
            for (int k = 0; k < 10; ++k) {
                float2 v = __half22float2(*(const __half2*)(wp + (hsub + k) * STG));
                rx[k] = v.x; ry[k] = v.y;
            }
            float sx = 0.f, sy = 0.f;
#pragma unroll
            for (int k = 0; k < 9; ++k) { sx += rx[k]; sy += ry[k]; }
            float tx2 = sx - rx[0] + rx[9];
            float ty2 = sy - ry[0] + ry[9];
            A[obase + (size_t)ch * VOLH2]            = __floats2half2_rn(sx, sy);
            A[obase + (size_t)ch * VOLH2 + DIM / 2]  = __floats2half2_rn(tx2, ty2);
        }
    }
}

__device__ inline void cc_accum(float s0, float s1, float s2, float s3,
                                float s4, float& acc) {
    const float inv_wsz = 1.0f / 729.0f;
    float cross = s4 - s0 * s1 * inv_wsz;
    float Ivar  = s2 - s0 * s0 * inv_wsz;
    float Jvar  = s3 - s1 * s1 * inv_wsz;
    float cc = cross * cross * __builtin_amdgcn_rcpf(Ivar * Jvar + 1e-5f);
    acc += fminf(fmaxf(cc, 0.0f), 1.0f);
}

__global__ __launch_bounds__(256) void k2_dsum_final(const __half2* __restrict__ Aall,
                                                     float* __restrict__ partial) {
    const int batch = blockIdx.y;
    const __half* B = (const __half*)(Aall + (size_t)batch * 5 * VOLH2);
    int t = blockIdx.x * 256 + threadIdx.x;  // < 40*160*8 = 51200
    int wq = t % (DIM / 4);                  // quad of 4 voxels along w
    int rest = t / (DIM / 4);
    int h = rest % DIM;
    int seg = rest / DIM;                    // 0..7
    int d0 = seg * SEG;
    const int base = h * DIM + wq * 4;       // half-element offset in a plane

    float4 s0 = {0,0,0,0}, s1 = {0,0,0,0}, s2 = {0,0,0,0},
           s3 = {0,0,0,0}, s4 = {0,0,0,0};
#define ACC4(sv, ch, idx, sgn)                                              \
    {                                                                       \
        float4 v_ = ld4h(B + (size_t)ch * VOL + (idx));                     \
        sv.x sgn v_.x; sv.y sgn v_.y; sv.z sgn v_.z; sv.w sgn v_.w;         \
    }
#pragma unroll
    for (int k = -4; k <= 4; ++k) {
        int dd = d0 + k;
        if (dd >= 0) {
            int idx = base + dd * HW;
            ACC4(s0, 0, idx, +=) ACC4(s1, 1, idx, +=) ACC4(s2, 2, idx, +=)
            ACC4(s3, 3, idx, +=) ACC4(s4, 4, idx, +=)
        }
    }

    float acc = 0.f;
    for (int d = d0; d < d0 + SEG; ++d) {
        cc_accum(s0.x, s1.x, s2.x, s3.x, s4.x, acc);
        cc_accum(s0.y, s1.y, s2.y, s3.y, s4.y, acc);
        cc_accum(s0.z, s1.z, s2.z, s3.z, s4.z, acc);
        cc_accum(s0.w, s1.w, s2.w, s3.w, s4.w, acc);
        int lead = d + 5, trail = d - 4;
        if (lead < DIM) {
            int li = base + lead * HW;
            ACC4(s0, 0, li, +=) ACC4(s1, 1, li, +=) ACC4(s2, 2, li, +=)
            ACC4(s3, 3, li, +=) ACC4(s4, 4, li, +=)
        }
        if (trail >= 0) {
            int ti = base + trail * HW;
            ACC4(s0, 0, ti, -=) ACC4(s1, 1, ti, -=) ACC4(s2, 2, ti, -=)
            ACC4(s3, 3, ti, -=) ACC4(s4, 4, ti, -=)
        }
    }
#undef ACC4

#pragma unroll
    for (int off = 32; off > 0; off >>= 1) acc += __shfl_down(acc, off);
    __shared__ float ws4[4];
    if ((threadIdx.x & 63) == 0) ws4[threadIdx.x >> 6] = acc;
    __syncthreads();
    if (threadIdx.x == 0)
        partial[batch * 200 + blockIdx.x] = ws4[0] + ws4[1] + ws4[2] + ws4[3];
}

__global__ __launch_bounds__(256) void final_reduce(const float* __restrict__ partial,
                                                    int n, float* __restrict__ out) {
    float a = 0.f;
    for (int i = threadIdx.x; i < n; i += 256) a += partial[i];
#pragma unroll
    for (int off = 32; off > 0; off >>= 1) a += __shfl_down(a, off);
    __shared__ float ws4[4];
    if ((threadIdx.x & 63) == 0) ws4[threadIdx.x >> 6] = a;
    __syncthreads();
    if (threadIdx.x == 0)
        out[0] = 1.0f - (ws4[0] + ws4[1] + ws4[2] + ws4[3]) *
                            (1.0f / (float)(NBATCH * VOL));
}

extern "C" void kernel_launch(void* const* d_in, const int* in_sizes, int n_in,
                              void* d_out, int out_size, void* d_ws, size_t ws_size,
                              hipStream_t stream) {
    const float* I = (const float*)d_in[0];
    const float* J = (const float*)d_in[1];
    float* out = (float*)d_out;

    __half2* A = (__half2*)d_ws;                        // [2][5][VOL] halves
    float* partial = (float*)((char*)d_ws +
                              (size_t)NBATCH * 5 * VOL * sizeof(__half)); // [400]

    dim3 g1(25, DIM, NBATCH);
    k1_boxsum2d<<<g1, 256, 0, stream>>>(I, J, A);
    dim3 g2(200, NBATCH);
    k2_dsum_final<<<g2, 256, 0, stream>>>(A, partial);
    final_reduce<<<1, 256, 0, stream>>>(partial, NBATCH * 200, out);
}

// Round 5
// 89.127 us; speedup vs baseline: 1.1588x; 1.1588x over previous
//
#include <hip/hip_runtime.h>
#include <hip/hip_fp16.h>

// NCC loss, window 9, zero-padded separable box sums.
// Shapes: (2,1,160,160,160) f32. Output: scalar f32.
//
// K1: per d-slice fused W+H 2D 9x9 box sum of 5 product channels.
//     W-stage loads its 12-float row segments DIRECTLY from global (no
//     sI/sJ LDS staging) -> LDS = 16 KB wsum only -> 8 blocks/CU.
//     wsum + intermediate A in fp16 (sums <= 81; rel err ~1e-3 ->
//     final loss err ~1e-5 vs 1.9e-2 threshold).
// K2: D-axis sliding-window sum, 2 voxels/thread, SEG=10 -> 1600 blocks
//     (6.25 waves/SIMD; K2 is parallelism-bound, round-4 lesson).
// ws layout: A[2][5][VOL] as half (82 MB) | partials[1600] f32

#define DIM 160
#define HW  (160 * 160)
#define VOL (160 * 160 * 160)
#define VOLH2 (VOL / 2)
#define HWH2 (HW / 2)
#define NBATCH 2
#define TIL 32
#define STG 40
#define SEG 10
#define NSEG (DIM / SEG)   // 16

struct __align__(8) h2q { __half2 a, b; };

__device__ inline float4 h2q_to_f4(h2q v) {
    float2 lo = __half22float2(v.a), hi = __half22float2(v.b);
    return make_float4(lo.x, lo.y, hi.x, hi.y);
}

__global__ __launch_bounds__(256) void k1_boxsum2d(const float* __restrict__ I,
                                                   const float* __restrict__ J,
                                                   __half2* __restrict__ A) {
    __shared__ __half wsumh[5][STG][STG];      // 16 KB

    const int tid = threadIdx.x;
    const int tx = blockIdx.x % 5, ty = blockIdx.x / 5;
    const int d = blockIdx.y;
    const int batch = blockIdx.z;
    const int h0 = ty * TIL, w0 = tx * TIL;
    const float* Ib = I + (size_t)batch * VOL + (size_t)d * HW;
    const float* Jb = J + (size_t)batch * VOL + (size_t)d * HW;

    // ---- W-stage: 40 rows x 8 col-groups; 12 floats straight from global ----
    for (int t = tid; t < 320; t += 256) {
        int r = t >> 3, g = t & 7;
        int gh = h0 - 4 + r;
        int gw = w0 - 4 + 4 * g;
        float a[12], b[12];
        if (gh >= 0 && gh < DIM) {
            const float* pI = Ib + gh * DIM;
            const float* pJ = Jb + gh * DIM;
            if (gw >= 0 && gw + 12 <= DIM) {
                *(float4*)&a[0] = *(const float4*)(pI + gw);
                *(float4*)&a[4] = *(const float4*)(pI + gw + 4);
                *(float4*)&a[8] = *(const float4*)(pI + gw + 8);
                *(float4*)&b[0] = *(const float4*)(pJ + gw);
                *(float4*)&b[4] = *(const float4*)(pJ + gw + 4);
                *(float4*)&b[8] = *(const float4*)(pJ + gw + 8);
            } else {
#pragma unroll
                for (int k = 0; k < 12; ++k) {
                    int c = gw + k;
                    bool ok = (c >= 0) && (c < DIM);
                    a[k] = ok ? pI[c] : 0.f;
                    b[k] = ok ? pJ[c] : 0.f;
                }
            }
        } else {
#pragma unroll
            for (int k = 0; k < 12; ++k) { a[k] = 0.f; b[k] = 0.f; }
        }

        float o0[4], o1[4], o2[4], o3[4], o4[4];
        float s0 = 0.f, s1 = 0.f, s2 = 0.f, s3 = 0.f, s4 = 0.f;
#pragma unroll
        for (int k = 0; k < 9; ++k) {
            float x = a[k], y = b[k];
            s0 += x; s1 += y; s2 += x * x; s3 += y * y; s4 += x * y;
        }
        o0[0] = s0; o1[0] = s1; o2[0] = s2; o3[0] = s3; o4[0] = s4;
#pragma unroll
        for (int j = 1; j < 4; ++j) {
            float xl = a[j + 8], yl = b[j + 8], xt = a[j - 1], yt = b[j - 1];
            s0 += xl - xt;
            s1 += yl - yt;
            s2 += xl * xl - xt * xt;
            s3 += yl * yl - yt * yt;
            s4 += xl * yl - xt * yt;
            o0[j] = s0; o1[j] = s1; o2[j] = s2; o3[j] = s3; o4[j] = s4;
        }
        __half* wp = &wsumh[0][0][0] + r * STG + 4 * g;
#define STORE_CH(ch, o)                                                     \
        {                                                                   \
            h2q q_;                                                         \
            q_.a = __floats2half2_rn(o[0], o[1]);                           \
            q_.b = __floats2half2_rn(o[2], o[3]);                           \
            *(h2q*)(wp + ch * (STG * STG)) = q_;                            \
        }
        STORE_CH(0, o0) STORE_CH(1, o1) STORE_CH(2, o2)
        STORE_CH(3, o3) STORE_CH(4, o4)
#undef STORE_CH
    }
    __syncthreads();

    // ---- H-stage: thread = (row h = tid>>3, cols 4q..4q+3, q = tid&7) ----
    {
        const int q = tid & 7, h = tid >> 3;
        float4 s[5];
#pragma unroll
        for (int c = 0; c < 5; ++c) s[c] = make_float4(0.f, 0.f, 0.f, 0.f);
#pragma unroll
        for (int k = 0; k < 9; ++k) {
            const __half* wp = &wsumh[0][h + k][4 * q];
#pragma unroll
            for (int c = 0; c < 5; ++c) {
                float4 v = h2q_to_f4(*(const h2q*)(wp + c * (STG * STG)));
                s[c].x += v.x; s[c].y += v.y; s[c].z += v.z; s[c].w += v.w;
            }
        }
        const size_t obase = (size_t)batch * 5 * VOLH2 + (size_t)d * HWH2 +
                             (size_t)(h0 + h) * (DIM / 2) + (size_t)(w0 / 2 + 2 * q);
#pragma unroll
        for (int c = 0; c < 5; ++c) {
            h2q q_;
            q_.a = __floats2half2_rn(s[c].x, s[c].y);
            q_.b = __floats2half2_rn(s[c].z, s[c].w);
            *(h2q*)&A[obase + (size_t)c * VOLH2] = q_;
        }
    }
}

__device__ inline void cc_accum(float s0, float s1, float s2, float s3,
                                float s4, float& acc) {
    const float inv_wsz = 1.0f / 729.0f;
    float cross = s4 - s0 * s1 * inv_wsz;
    float Ivar  = s2 - s0 * s0 * inv_wsz;
    float Jvar  = s3 - s1 * s1 * inv_wsz;
    float cc = cross * cross * __builtin_amdgcn_rcpf(Ivar * Jvar + 1e-5f);
    acc += fminf(fmaxf(cc, 0.0f), 1.0f);
}

__global__ __launch_bounds__(256) void k2_dsum_final(const __half2* __restrict__ Aall,
                                                     float* __restrict__ partial) {
    const int batch = blockIdx.y;
    const __half2* B = Aall + (size_t)batch * 5 * VOLH2;
    int t = blockIdx.x * 256 + threadIdx.x;  // < 80*160*16 = 204800
    int wq = t % (DIM / 2);
    int rest = t / (DIM / 2);
    int h = rest % DIM;
    int seg = rest / DIM;                    // 0..15
    int d0 = seg * SEG;
    const int base = h * (DIM / 2) + wq;

    float2 s0 = {0.f, 0.f}, s1 = {0.f, 0.f}, s2 = {0.f, 0.f},
           s3 = {0.f, 0.f}, s4 = {0.f, 0.f};
#pragma unroll
    for (int k = -4; k <= 4; ++k) {
        int dd = d0 + k;
        if (dd >= 0) {
            int idx = base + dd * HWH2;
            float2 v;
            v = __half22float2(B[0 * VOLH2 + idx]); s0.x += v.x; s0.y += v.y;
            v = __half22float2(B[1 * VOLH2 + idx]); s1.x += v.x; s1.y += v.y;
            v = __half22float2(B[2 * VOLH2 + idx]); s2.x += v.x; s2.y += v.y;
            v = __half22float2(B[3 * VOLH2 + idx]); s3.x += v.x; s3.y += v.y;
            v = __half22float2(B[4 * VOLH2 + idx]); s4.x += v.x; s4.y += v.y;
        }
    }

    float acc = 0.f;
    for (int d = d0; d < d0 + SEG; ++d) {
        cc_accum(s0.x, s1.x, s2.x, s3.x, s4.x, acc);
        cc_accum(s0.y, s1.y, s2.y, s3.y, s4.y, acc);
        int lead = d + 5, trail = d - 4;
        if (lead < DIM) {
            int li = base + lead * HWH2;
            float2 v;
            v = __half22float2(B[0 * VOLH2 + li]); s0.x += v.x; s0.y += v.y;
            v = __half22float2(B[1 * VOLH2 + li]); s1.x += v.x; s1.y += v.y;
            v = __half22float2(B[2 * VOLH2 + li]); s2.x += v.x; s2.y += v.y;
            v = __half22float2(B[3 * VOLH2 + li]); s3.x += v.x; s3.y += v.y;
            v = __half22float2(B[4 * VOLH2 + li]); s4.x += v.x; s4.y += v.y;
        }
        if (trail >= 0) {
            int ti = base + trail * HWH2;
            float2 v;
            v = __half22float2(B[0 * VOLH2 + ti]); s0.x -= v.x; s0.y -= v.y;
            v = __half22float2(B[1 * VOLH2 + ti]); s1.x -= v.x; s1.y -= v.y;
            v = __half22float2(B[2 * VOLH2 + ti]); s2.x -= v.x; s2.y -= v.y;
            v = __half22float2(B[3 * VOLH2 + ti]); s3.x -= v.x; s3.y -= v.y;
            v = __half22float2(B[4 * VOLH2 + ti]); s4.x -= v.x; s4.y -= v.y;
        }
    }

#pragma unroll
    for (int off = 32; off > 0; off >>= 1) acc += __shfl_down(acc, off);
    __shared__ float ws4[4];
    if ((threadIdx.x & 63) == 0) ws4[threadIdx.x >> 6] = acc;
    __syncthreads();
    if (threadIdx.x == 0)
        partial[batch * 800 + blockIdx.x] = ws4[0] + ws4[1] + ws4[2] + ws4[3];
}

__global__ __launch_bounds__(256) void final_reduce(const float* __restrict__ partial,
                                                    int n, float* __restrict__ out) {
    float a = 0.f;
    for (int i = threadIdx.x; i < n; i += 256) a += partial[i];
#pragma unroll
    for (int off = 32; off > 0; off >>= 1) a += __shfl_down(a, off);
    __shared__ float ws4[4];
    if ((threadIdx.x & 63) == 0) ws4[threadIdx.x >> 6] = a;
    __syncthreads();
    if (threadIdx.x == 0)
        out[0] = 1.0f - (ws4[0] + ws4[1] + ws4[2] + ws4[3]) *
                            (1.0f / (float)(NBATCH * VOL));
}

extern "C" void kernel_launch(void* const* d_in, const int* in_sizes, int n_in,
                              void* d_out, int out_size, void* d_ws, size_t ws_size,
                              hipStream_t stream) {
    const float* I = (const float*)d_in[0];
    const float* J = (const float*)d_in[1];
    float* out = (float*)d_out;

    __half2* A = (__half2*)d_ws;                        // [2][5][VOL] halves
    float* partial = (float*)((char*)d_ws +
                              (size_t)NBATCH * 5 * VOL * sizeof(__half)); // [1600]

    dim3 g1(25, DIM, NBATCH);
    k1_boxsum2d<<<g1, 256, 0, stream>>>(I, J, A);
    dim3 g2(800, NBATCH);
    k2_dsum_final<<<g2, 256, 0, stream>>>(A, partial);
    final_reduce<<<1, 256, 0, stream>>>(partial, NBATCH * 800, out);
}

// Round 6
// 75.526 us; speedup vs baseline: 1.3675x; 1.1801x over previous
//
#include <hip/hip_runtime.h>
#include <hip/hip_fp16.h>

// NCC loss, window 9, zero-padded separable box sums.
// Shapes: (2,1,160,160,160) f32. Output: scalar f32.
//
// K1: per d-slice fused W+H 2D 9x9 box sum of 5 product channels.
//     Tile = full 160w x 16h, 320 threads. W-stage: 8-output sliding
//     tasks, loads direct from global. H-stage: 4-row slide per thread
//     in PACKED fp16 (hadd2/hsub2, no conversions). LDS = wsum 38.4 KB.
//     All LDS access contiguous -> no bank conflicts.
// K2: D-axis sliding-window sum, 2 voxels/thread, SEG=10 (parallelism-
//     bound lesson from round 4).
// ws layout: A[2][5][VOL] as half (82 MB) | partials[1600] f32

#define DIM 160
#define HW  (160 * 160)
#define VOL (160 * 160 * 160)
#define VOLH2 (VOL / 2)
#define HWH2 (HW / 2)
#define NBATCH 2
#define TH 16                  // output rows per K1 block
#define RST 24                 // staged rows = TH + 8
#define THB 320                // K1 threads per block
#define SEG 10
#define NSEG (DIM / SEG)       // 16

struct __align__(16) h4q { __half2 a, b, c, d; };

__global__ __launch_bounds__(THB) void k1_boxsum2d(const float* __restrict__ I,
                                                   const float* __restrict__ J,
                                                   __half2* __restrict__ A) {
    __shared__ __half wsumh[5][RST][DIM];      // 38400 B

    const int tid = threadIdx.x;
    const int ty = blockIdx.x;       // 0..9
    const int d = blockIdx.y;
    const int batch = blockIdx.z;
    const int h0 = ty * TH;
    const float* Ib = I + (size_t)batch * VOL + (size_t)d * HW;
    const float* Jb = J + (size_t)batch * VOL + (size_t)d * HW;

    // ---- W-stage: 24 rows x 20 groups of 8 outputs, sliding ----
    for (int t = tid; t < 480; t += THB) {
        int r = t / 20, g = t % 20;
        int gh = h0 - 4 + r;
        int gw = 8 * g - 4;          // multiple of 4 -> float4-aligned
        __half* wrow = &wsumh[0][r][8 * g];

        if (gh < 0 || gh >= DIM) {
            __half2 z2 = __float2half2_rn(0.f);
            h4q z; z.a = z2; z.b = z2; z.c = z2; z.d = z2;
#pragma unroll
            for (int ch = 0; ch < 5; ++ch)
                *(h4q*)(wrow + ch * (RST * DIM)) = z;
            continue;
        }

        const float* pI = Ib + gh * DIM;
        const float* pJ = Jb + gh * DIM;
        float a[16], b[16];
#pragma unroll
        for (int q = 0; q < 4; ++q) {
            int c = gw + 4 * q;      // fully in [0,160) or fully outside
            if (c >= 0 && c < DIM) {
                *(float4*)&a[4 * q] = *(const float4*)(pI + c);
                *(float4*)&b[4 * q] = *(const float4*)(pJ + c);
            } else {
                *(float4*)&a[4 * q] = make_float4(0.f, 0.f, 0.f, 0.f);
                *(float4*)&b[4 * q] = make_float4(0.f, 0.f, 0.f, 0.f);
            }
        }

#define PROC(CH, VAL)                                                       \
        {                                                                   \
            float o[8];                                                     \
            float s = 0.f;                                                  \
            _Pragma("unroll")                                               \
            for (int k = 0; k < 9; ++k) { s += (VAL); }                     \
            o[0] = s;                                                       \
            _Pragma("unroll")                                               \
            for (int j = 1; j < 8; ++j) {                                   \
                int k = j + 8; float add_ = (VAL);                          \
                k = j - 1;     float sub_ = (VAL);                          \
                s += add_ - sub_;                                           \
                o[j] = s;                                                   \
            }                                                               \
            h4q v;                                                          \
            v.a = __floats2half2_rn(o[0], o[1]);                            \
            v.b = __floats2half2_rn(o[2], o[3]);                            \
            v.c = __floats2half2_rn(o[4], o[5]);                            \
            v.d = __floats2half2_rn(o[6], o[7]);                            \
            *(h4q*)(wrow + CH * (RST * DIM)) = v;                           \
        }
        PROC(0, a[k])
        PROC(1, b[k])
        PROC(2, a[k] * a[k])
        PROC(3, b[k] * b[k])
        PROC(4, a[k] * b[k])
#undef PROC
    }
    __syncthreads();

    // ---- H-stage: thread = (w-pair wp, h-group of 4), packed fp16 slide ----
    {
        const int wp = tid % 80;     // half2 index along w
        const int hg = tid / 80;     // 0..3
        const __half2* w2 = (const __half2*)&wsumh[0][0][0];  // [5][24][80]
        const size_t ob = (size_t)batch * 5 * VOLH2 + (size_t)d * HWH2 +
                          (size_t)(h0 + 4 * hg) * (DIM / 2) + wp;
#pragma unroll
        for (int c = 0; c < 5; ++c) {
            const __half2* col = w2 + ((size_t)c * RST + 4 * hg) * 80 + wp;
            __half2 s = __float2half2_rn(0.f);
#pragma unroll
            for (int k = 0; k < 9; ++k) s = __hadd2(s, col[k * 80]);
            __half2* Ao = &A[ob + (size_t)c * VOLH2];
            Ao[0] = s;
#pragma unroll
            for (int j = 1; j < 4; ++j) {
                s = __hadd2(__hsub2(s, col[(j - 1) * 80]), col[(j + 8) * 80]);
                Ao[(size_t)j * (DIM / 2)] = s;
            }
        }
    }
}

__device__ inline void cc_accum(float s0, float s1, float s2, float s3,
                                float s4, float& acc) {
    const float inv_wsz = 1.0f / 729.0f;
    float cross = s4 - s0 * s1 * inv_wsz;
    float Ivar  = s2 - s0 * s0 * inv_wsz;
    float Jvar  = s3 - s1 * s1 * inv_wsz;
    float cc = cross * cross * __builtin_amdgcn_rcpf(Ivar * Jvar + 1e-5f);
    acc += fminf(fmaxf(cc, 0.0f), 1.0f);
}

__global__ __launch_bounds__(256) void k2_dsum_final(const __half2* __restrict__ Aall,
                                                     float* __restrict__ partial) {
    const int batch = blockIdx.y;
    const __half2* B = Aall + (size_t)batch * 5 * VOLH2;
    int t = blockIdx.x * 256 + threadIdx.x;  // < 80*160*16 = 204800
    int wq = t % (DIM / 2);
    int rest = t / (DIM / 2);
    int h = rest % DIM;
    int seg = rest / DIM;                    // 0..15
    int d0 = seg * SEG;
    const int base = h * (DIM / 2) + wq;

    float2 s0 = {0.f, 0.f}, s1 = {0.f, 0.f}, s2 = {0.f, 0.f},
           s3 = {0.f, 0.f}, s4 = {0.f, 0.f};
#pragma unroll
    for (int k = -4; k <= 4; ++k) {
        int dd = d0 + k;
        if (dd >= 0) {
            int idx = base + dd * HWH2;
            float2 v;
            v = __half22float2(B[0 * VOLH2 + idx]); s0.x += v.x; s0.y += v.y;
            v = __half22float2(B[1 * VOLH2 + idx]); s1.x += v.x; s1.y += v.y;
            v = __half22float2(B[2 * VOLH2 + idx]); s2.x += v.x; s2.y += v.y;
            v = __half22float2(B[3 * VOLH2 + idx]); s3.x += v.x; s3.y += v.y;
            v = __half22float2(B[4 * VOLH2 + idx]); s4.x += v.x; s4.y += v.y;
        }
    }

    float acc = 0.f;
    for (int d = d0; d < d0 + SEG; ++d) {
        cc_accum(s0.x, s1.x, s2.x, s3.x, s4.x, acc);
        cc_accum(s0.y, s1.y, s2.y, s3.y, s4.y, acc);
        int lead = d + 5, trail = d - 4;
        if (lead < DIM) {
            int li = base + lead * HWH2;
            float2 v;
            v = __half22float2(B[0 * VOLH2 + li]); s0.x += v.x; s0.y += v.y;
            v = __half22float2(B[1 * VOLH2 + li]); s1.x += v.x; s1.y += v.y;
            v = __half22float2(B[2 * VOLH2 + li]); s2.x += v.x; s2.y += v.y;
            v = __half22float2(B[3 * VOLH2 + li]); s3.x += v.x; s3.y += v.y;
            v = __half22float2(B[4 * VOLH2 + li]); s4.x += v.x; s4.y += v.y;
        }
        if (trail >= 0) {
            int ti = base + trail * HWH2;
            float2 v;
            v = __half22float2(B[0 * VOLH2 + ti]); s0.x -= v.x; s0.y -= v.y;
            v = __half22float2(B[1 * VOLH2 + ti]); s1.x -= v.x; s1.y -= v.y;
            v = __half22float2(B[2 * VOLH2 + ti]); s2.x -= v.x; s2.y -= v.y;
            v = __half22float2(B[3 * VOLH2 + ti]); s3.x -= v.x; s3.y -= v.y;
            v = __half22float2(B[4 * VOLH2 + ti]); s4.x -= v.x; s4.y -= v.y;
        }
    }

#pragma unroll
    for (int off = 32; off > 0; off >>= 1) acc += __shfl_down(acc, off);
    __shared__ float ws4[4];
    if ((threadIdx.x & 63) == 0) ws4[threadIdx.x >> 6] = acc;
    __syncthreads();
    if (threadIdx.x == 0)
        partial[batch * 800 + blockIdx.x] = ws4[0] + ws4[1] + ws4[2] + ws4[3];
}

__global__ __launch_bounds__(256) void final_reduce(const float* __restrict__ partial,
                                                    int n, float* __restrict__ out) {
    float a = 0.f;
    for (int i = threadIdx.x; i < n; i += 256) a += partial[i];
#pragma unroll
    for (int off = 32; off > 0; off >>= 1) a += __shfl_down(a, off);
    __shared__ float ws4[4];
    if ((threadIdx.x & 63) == 0) ws4[threadIdx.x >> 6] = a;
    __syncthreads();
    if (threadIdx.x == 0)
        out[0] = 1.0f - (ws4[0] + ws4[1] + ws4[2] + ws4[3]) *
                            (1.0f / (float)(NBATCH * VOL));
}

extern "C" void kernel_launch(void* const* d_in, const int* in_sizes, int n_in,
                              void* d_out, int out_size, void* d_ws, size_t ws_size,
                              hipStream_t stream) {
    const float* I = (const float*)d_in[0];
    const float* J = (const float*)d_in[1];
    float* out = (float*)d_out;

    __half2* A = (__half2*)d_ws;                        // [2][5][VOL] halves
    float* partial = (float*)((char*)d_ws +
                              (size_t)NBATCH * 5 * VOL * sizeof(__half)); // [1600]

    dim3 g1(10, DIM, NBATCH);
    k1_boxsum2d<<<g1, THB, 0, stream>>>(I, J, A);
    dim3 g2(800, NBATCH);
    k2_dsum_final<<<g2, 256, 0, stream>>>(A, partial);
    final_reduce<<<1, 256, 0, stream>>>(partial, NBATCH * 800, out);
}